// Round 12
// baseline (228.114 us; speedup 1.0000x reference)
//
#include <hip/hip_runtime.h>
#include <cmath>

typedef __attribute__((ext_vector_type(8))) __bf16 bf16x8;
typedef __attribute__((ext_vector_type(4))) __bf16 bf16x4;
typedef __attribute__((ext_vector_type(4))) float  f32x4;

constexpr int NB   = 4;
constexpr int SEQ  = 2048;
constexpr int DM   = 256;
constexpr int NH   = 8;
constexpr int DH   = 32;
constexpr int DFF  = 1024;
constexpr int MTOK = NB * SEQ;  // 8192

// ---------------- LayerNorm: fp32 [rows][256] -> bf16 [rows][256] ----------------
__global__ __launch_bounds__(256) void ln_kernel(const float* __restrict__ x,
                                                 const float* __restrict__ g,
                                                 const float* __restrict__ b,
                                                 __bf16* __restrict__ out) {
  int wave = threadIdx.x >> 6, lane = threadIdx.x & 63;
  int row = blockIdx.x * 4 + wave;
  const float* xr = x + (size_t)row * DM;
  f32x4 v = *(const f32x4*)(xr + lane * 4);
  float s  = v[0] + v[1] + v[2] + v[3];
  float sq = v[0]*v[0] + v[1]*v[1] + v[2]*v[2] + v[3]*v[3];
  #pragma unroll
  for (int off = 1; off < 64; off <<= 1) {
    s  += __shfl_xor(s, off);
    sq += __shfl_xor(sq, off);
  }
  float mu  = s * (1.0f / DM);
  float var = sq * (1.0f / DM) - mu * mu;
  float rs  = rsqrtf(var + 1e-5f);
  f32x4 gv = *(const f32x4*)(g + lane * 4);
  f32x4 bv = *(const f32x4*)(b + lane * 4);
  bf16x4 o;
  #pragma unroll
  for (int i = 0; i < 4; ++i) o[i] = (__bf16)((v[i] - mu) * rs * gv[i] + bv[i]);
  *(bf16x4*)(out + (size_t)row * DM + lane * 4) = o;
}

// ---------------- Fused prep, TIGHT 1D grid (2848 blocks) ----------------
__global__ __launch_bounds__(256) void prep_kernel(
    const float* __restrict__ wq, const float* __restrict__ wk, const float* __restrict__ wv,
    const float* __restrict__ wo, const float* __restrict__ w1, const float* __restrict__ w2,
    const unsigned char* __restrict__ mask, const float* __restrict__ tokens,
    const float* __restrict__ ln1g, const float* __restrict__ ln1b,
    __bf16* __restrict__ wqkvT, __bf16* __restrict__ woT,
    __bf16* __restrict__ w1T, __bf16* __restrict__ w2T,
    float* __restrict__ madd_g, __bf16* __restrict__ xn1) {
  __shared__ float tile[32][33];
  int bid = blockIdx.x;
  int tid = threadIdx.x;
  if (bid >= 800) {
    int row = (bid - 800) * 4 + (tid >> 6);
    int lane = tid & 63;
    const float* xr = tokens + (size_t)row * DM;
    f32x4 v = *(const f32x4*)(xr + lane * 4);
    float s  = v[0] + v[1] + v[2] + v[3];
    float sq = v[0]*v[0] + v[1]*v[1] + v[2]*v[2] + v[3]*v[3];
    #pragma unroll
    for (int off = 1; off < 64; off <<= 1) {
      s  += __shfl_xor(s, off);
      sq += __shfl_xor(sq, off);
    }
    float mu  = s * (1.0f / DM);
    float var = sq * (1.0f / DM) - mu * mu;
    float rs  = rsqrtf(var + 1e-5f);
    f32x4 gv = *(const f32x4*)(ln1g + lane * 4);
    f32x4 bv = *(const f32x4*)(ln1b + lane * 4);
    bf16x4 o;
    #pragma unroll
    for (int i = 0; i < 4; ++i) o[i] = (__bf16)((v[i] - mu) * rs * gv[i] + bv[i]);
    *(bf16x4*)(xn1 + (size_t)row * DM + lane * 4) = o;
    return;
  }
  if (bid >= 768) {
    int idx = (bid - 768) * 256 + tid;
    madd_g[idx] = mask[idx] ? -__builtin_inff() : 0.0f;
    return;
  }
  const float* W; __bf16* Wt; int K, N, n0, k0;
  if (bid < 256) {
    int z = bid >> 6, local = bid & 63;
    K = 256; N = 256;
    n0 = (local & 7) * 32; k0 = (local >> 3) * 32;
    if      (z == 0) { W = wq; Wt = wqkvT;          }
    else if (z == 1) { W = wk; Wt = wqkvT + 65536;  }
    else if (z == 2) { W = wv; Wt = wqkvT + 131072; }
    else             { W = wo; Wt = woT;            }
  } else if (bid < 512) {
    int local = bid - 256;
    W = w1; Wt = w1T; K = 256; N = 1024;
    n0 = (local & 31) * 32; k0 = (local >> 5) * 32;
  } else {
    int local = bid - 512;
    W = w2; Wt = w2T; K = 1024; N = 256;
    n0 = (local & 7) * 32; k0 = (local >> 3) * 32;
  }
  {
    int kl = tid >> 3, n4 = (tid & 7) * 4;
    f32x4 v = *(const f32x4*)(W + (size_t)(k0 + kl) * N + n0 + n4);
    tile[kl][n4 + 0] = v[0]; tile[kl][n4 + 1] = v[1];
    tile[kl][n4 + 2] = v[2]; tile[kl][n4 + 3] = v[3];
  }
  __syncthreads();
  {
    int nl = tid >> 3, k4 = (tid & 7) * 4;
    bf16x4 o;
    #pragma unroll
    for (int i = 0; i < 4; ++i) o[i] = (__bf16)tile[k4 + i][nl];
    *(bf16x4*)(Wt + (size_t)(n0 + nl) * K + k0 + k4) = o;
  }
}

// ---------------- Register-B streaming GEMM (K=256): zero LDS, zero barriers ----------------
// Wave holds its 32-col B-slice (16 KB) entirely in 64 VGPRs; streams MITERS
// 32-row M-tiles: 16 direct global A-frag loads -> 32 dense MFMAs -> epilogue.
// EP 0: QKV (+bias, scatter Q,K->[bh][tok][hd], V->Vt[bh][hd][tok])
// EP 1: Wo (+fused split-K reduce A-build, +bias +resid -> fp32)
// EP 2: FF1 (+bias, tanh-GELU -> bf16)
template<int EP, int MITERS>
__global__ __launch_bounds__(256) void gemm_regb(
    const __bf16* __restrict__ A, const __bf16* __restrict__ Bt, int N,
    const float* __restrict__ bias,
    const float* __restrict__ bq, const float* __restrict__ bk, const float* __restrict__ bv,
    const float* __restrict__ resid, float* __restrict__ outf, __bf16* __restrict__ outb,
    __bf16* __restrict__ outq, __bf16* __restrict__ outk, __bf16* __restrict__ outv,
    const float* __restrict__ Af, const float* __restrict__ lpart) {
  constexpr int KD = 256, KS = 8;
  int wglob = blockIdx.x * 4 + (threadIdx.x >> 6);
  int lane = threadIdx.x & 63;
  int quad = lane >> 4, l16 = lane & 15;
  int nslices = N >> 5;
  int nsl = wglob % nslices;
  int mch = wglob / nslices;
  int n0 = nsl * 32;

  // B-slice -> registers (once per wave)
  bf16x8 bfrag[2][KS];
  #pragma unroll
  for (int nt = 0; nt < 2; ++nt)
    #pragma unroll
    for (int ks = 0; ks < KS; ++ks)
      bfrag[nt][ks] = *(const bf16x8*)(Bt + (size_t)(n0 + nt * 16 + l16) * KD + ks * 32 + quad * 8);

  #pragma unroll
  for (int it = 0; it < MITERS; ++it) {
    int m0 = (mch * MITERS + it) * 32;

    bf16x8 af[2][KS];
    if constexpr (EP == 1) {
      // A built on the fly from split-K attention partials (h == ks for DH=32)
      #pragma unroll
      for (int am = 0; am < 2; ++am) {
        int gr = m0 + am * 16 + l16;
        int bb = gr >> 11, tok = gr & 2047;
        #pragma unroll
        for (int ks = 0; ks < KS; ++ks) {
          const float* p0 = Af + (size_t)gr * KD + ks * 32 + quad * 8;
          const float* p1 = p0 + (size_t)MTOK * DM;
          f32x4 a0 = *(const f32x4*)p0, a0b = *(const f32x4*)(p0 + 4);
          f32x4 a1 = *(const f32x4*)p1, a1b = *(const f32x4*)(p1 + 4);
          float l = lpart[((size_t)bb * NH + ks) * SEQ + tok] +
                    lpart[(((size_t)NB + bb) * NH + ks) * SEQ + tok];
          float inv = 1.0f / l;
          bf16x8 o;
          #pragma unroll
          for (int i = 0; i < 4; ++i) {
            o[i]     = (__bf16)((a0[i]  + a1[i])  * inv);
            o[i + 4] = (__bf16)((a0b[i] + a1b[i]) * inv);
          }
          af[am][ks] = o;
        }
      }
    } else {
      #pragma unroll
      for (int am = 0; am < 2; ++am)
        #pragma unroll
        for (int ks = 0; ks < KS; ++ks)
          af[am][ks] = *(const bf16x8*)(A + (size_t)(m0 + am * 16 + l16) * KD + ks * 32 + quad * 8);
    }

    f32x4 acc[2][2];
    #pragma unroll
    for (int am = 0; am < 2; ++am)
      #pragma unroll
      for (int nt = 0; nt < 2; ++nt)
        #pragma unroll
        for (int r = 0; r < 4; ++r) acc[am][nt][r] = 0.0f;

    #pragma unroll
    for (int ks = 0; ks < KS; ++ks)
      #pragma unroll
      for (int am = 0; am < 2; ++am)
        #pragma unroll
        for (int nt = 0; nt < 2; ++nt)
          acc[am][nt] = __builtin_amdgcn_mfma_f32_16x16x32_bf16(af[am][ks], bfrag[nt][ks], acc[am][nt], 0, 0, 0);

    #pragma unroll
    for (int am = 0; am < 2; ++am)
    #pragma unroll
    for (int nt = 0; nt < 2; ++nt)
    #pragma unroll
    for (int r = 0; r < 4; ++r) {
      int gm = m0 + am * 16 + quad * 4 + r;
      int gn = n0 + nt * 16 + l16;
      float v = acc[am][nt][r];
      if constexpr (EP == 0) {
        int which = gn >> 8, nn = gn & 255;
        const float* bp2 = which == 0 ? bq : (which == 1 ? bk : bv);
        v += bp2[nn];
        int h = nn >> 5, hd = nn & 31;
        int bb = gm >> 11, tok = gm & 2047;
        if (which == 2) {
          outv[(((size_t)(bb * NH + h)) * DH + hd) * SEQ + tok] = (__bf16)v;
        } else {
          __bf16* dst = which == 0 ? outq : outk;
          dst[(((size_t)(bb * NH + h)) * SEQ + tok) * DH + hd] = (__bf16)v;
        }
      } else if constexpr (EP == 1) {
        v += bias[gn] + resid[(size_t)gm * DM + gn];
        outf[(size_t)gm * DM + gn] = v;
      } else {
        v += bias[gn];
        float v2 = v * v;
        float t = __builtin_amdgcn_exp2f(v * (2.3022082f + 0.10294324f * v2));
        outb[(size_t)gm * N + gn] = (__bf16)(v * t * __builtin_amdgcn_rcpf(t + 1.0f));
      }
    }
  }
}

// ---------------- LDS-staged GEMM (kept for FF2, K=1024) ----------------
template<int BM, int BN, int EP>
__global__ __launch_bounds__(256) void gemm_bt(
    const __bf16* __restrict__ A, const __bf16* __restrict__ Bt,
    int M, int N, int K,
    const float* __restrict__ bias,
    const float* __restrict__ resid, float* __restrict__ outf) {
  constexpr int MT = BM / 32, NT = BN / 32;
  constexpr int AP = BM / 32, BP = BN / 32;
  __shared__ __bf16 As[BM * 64];
  __shared__ __bf16 Bs[BN * 64];
  int tid = threadIdx.x;
  int wave = tid >> 6, lane = tid & 63;
  int wm = wave >> 1, wn = wave & 1;
  int quad = lane >> 4, l16 = lane & 15;
  int m0 = blockIdx.x * BM, n0 = blockIdx.y * BN;
  int lrow = lane >> 3;
  int lcg  = ((lane & 7) ^ lrow) * 8;

  f32x4 acc[MT][NT];
  #pragma unroll
  for (int mt = 0; mt < MT; ++mt)
    #pragma unroll
    for (int nt = 0; nt < NT; ++nt)
      #pragma unroll
      for (int r = 0; r < 4; ++r) acc[mt][nt][r] = 0.0f;

  bf16x8 ap[AP], bp[BP];
  #pragma unroll
  for (int i = 0; i < AP; ++i) {
    int rbase = wave * (BM / 4) + i * 8;
    ap[i] = *(const bf16x8*)(A + (size_t)(m0 + rbase + lrow) * K + lcg);
  }
  #pragma unroll
  for (int i = 0; i < BP; ++i) {
    int rbase = wave * (BN / 4) + i * 8;
    bp[i] = *(const bf16x8*)(Bt + (size_t)(n0 + rbase + lrow) * K + lcg);
  }
  #pragma unroll
  for (int i = 0; i < AP; ++i) {
    int rbase = wave * (BM / 4) + i * 8;
    *(bf16x8*)&As[rbase * 64 + lane * 8] = ap[i];
  }
  #pragma unroll
  for (int i = 0; i < BP; ++i) {
    int rbase = wave * (BN / 4) + i * 8;
    *(bf16x8*)&Bs[rbase * 64 + lane * 8] = bp[i];
  }
  __syncthreads();

  for (int kt = 0; kt < K; kt += 64) {
    bool more = (kt + 64) < K;
    if (more) {
      #pragma unroll
      for (int i = 0; i < AP; ++i) {
        int rbase = wave * (BM / 4) + i * 8;
        ap[i] = *(const bf16x8*)(A + (size_t)(m0 + rbase + lrow) * K + kt + 64 + lcg);
      }
      #pragma unroll
      for (int i = 0; i < BP; ++i) {
        int rbase = wave * (BN / 4) + i * 8;
        bp[i] = *(const bf16x8*)(Bt + (size_t)(n0 + rbase + lrow) * K + kt + 64 + lcg);
      }
    }
    #pragma unroll
    for (int ks = 0; ks < 2; ++ks) {
      bf16x8 af[MT], bfr[NT];
      #pragma unroll
      for (int mt = 0; mt < MT; ++mt) {
        int row = wm * (BM / 2) + mt * 16 + l16;
        af[mt] = *(const bf16x8*)&As[row * 64 + (((ks * 4 + quad) ^ (l16 & 7)) * 8)];
      }
      #pragma unroll
      for (int nt = 0; nt < NT; ++nt) {
        int row = wn * (BN / 2) + nt * 16 + l16;
        bfr[nt] = *(const bf16x8*)&Bs[row * 64 + (((ks * 4 + quad) ^ (l16 & 7)) * 8)];
      }
      #pragma unroll
      for (int mt = 0; mt < MT; ++mt)
        #pragma unroll
        for (int nt = 0; nt < NT; ++nt)
          acc[mt][nt] = __builtin_amdgcn_mfma_f32_16x16x32_bf16(af[mt], bfr[nt], acc[mt][nt], 0, 0, 0);
    }
    if (more) {
      __syncthreads();
      #pragma unroll
      for (int i = 0; i < AP; ++i) {
        int rbase = wave * (BM / 4) + i * 8;
        *(bf16x8*)&As[rbase * 64 + lane * 8] = ap[i];
      }
      #pragma unroll
      for (int i = 0; i < BP; ++i) {
        int rbase = wave * (BN / 4) + i * 8;
        *(bf16x8*)&Bs[rbase * 64 + lane * 8] = bp[i];
      }
      __syncthreads();
    }
  }

  #pragma unroll
  for (int mt = 0; mt < MT; ++mt)
  #pragma unroll
  for (int nt = 0; nt < NT; ++nt)
  #pragma unroll
  for (int r = 0; r < 4; ++r) {
    int gm = m0 + wm * (BM / 2) + mt * 16 + quad * 4 + r;
    int gn = n0 + wn * (BN / 2) + nt * 16 + l16;
    float v = acc[mt][nt][r] + bias[gn] + resid[(size_t)gm * N + gn];
    outf[(size_t)gm * N + gn] = v;
  }
}

// ---------------- Flash attention (R10 exact): 32 q/wave, shared 128-key stages, split-K=2 ----------------
__global__ __launch_bounds__(256) void attn_kernel(
    const __bf16* __restrict__ Q, const __bf16* __restrict__ K,
    const __bf16* __restrict__ Vt, const float* __restrict__ madd_g,
    float* __restrict__ Opart, float* __restrict__ lpart) {
  constexpr float C2 = 0.2550350030061664f;  // (1/sqrt(32)) * log2(e)
  __shared__ __bf16 Ks[128][36];      // [key][dh], 72B stride
  __shared__ __bf16 Vs[32][132];      // [dh][key], 264B stride
  __shared__ __bf16 Ps[4][2][16][68]; // [wave][qg][query][key]
  int bh = blockIdx.x;
  int q0 = blockIdx.y * 128;
  int half = blockIdx.z;
  int b  = bh >> 3, h = bh & 7;
  int tid = threadIdx.x;
  int wave = tid >> 6, lane = tid & 63;
  int quad = lane >> 4, l16 = lane & 15;
  const __bf16* Qb = Q  + (size_t)bh * SEQ * DH;
  const __bf16* Kb = K  + (size_t)bh * SEQ * DH;
  const __bf16* Vb = Vt + (size_t)bh * DH * SEQ;
  const float* maddb = madd_g + b * SEQ;
  int qw = q0 + wave * 32;
  int kbase = half * (SEQ / 2);

  bf16x8 qf[2];
  #pragma unroll
  for (int qg = 0; qg < 2; ++qg)
    qf[qg] = *(const bf16x8*)(Qb + (size_t)(qw + qg * 16 + l16) * DH + quad * 8);

  bf16x8 ones;
  #pragma unroll
  for (int i = 0; i < 8; ++i) ones[i] = (__bf16)1.0f;

  f32x4 o[2][2], ol[2];
  #pragma unroll
  for (int qg = 0; qg < 2; ++qg) {
    #pragma unroll
    for (int nt = 0; nt < 2; ++nt)
      #pragma unroll
      for (int r = 0; r < 4; ++r) o[qg][nt][r] = 0.0f;
    #pragma unroll
    for (int r = 0; r < 4; ++r) ol[qg][r] = 0.0f;
  }

  f32x4 zf; zf[0] = zf[1] = zf[2] = zf[3] = 0.0f;

  for (int st = 0; st < 8; ++st) {          // 8 stages x 128 keys = this half
    int kb0 = kbase + st * 128;
    __syncthreads();
    #pragma unroll
    for (int p = 0; p < 2; ++p) {           // stage K: 128 rows x 64B
      int c = p * 256 + tid, row = c >> 2, cg = (c & 3) * 8;
      *(bf16x8*)&Ks[row][cg] = *(const bf16x8*)(Kb + (size_t)(kb0 + row) * DH + cg);
    }
    #pragma unroll
    for (int p = 0; p < 2; ++p) {           // stage V: 32 rows x 256B
      int c = p * 256 + tid, row = c >> 4, cg = (c & 15) * 8;
      *(bf16x8*)&Vs[row][cg] = *(const bf16x8*)(Vb + (size_t)row * SEQ + kb0 + cg);
    }
    __syncthreads();

    #pragma unroll
    for (int sub = 0; sub < 2; ++sub) {     // 2 x 64-key subtiles
      int kl = sub * 64;
      f32x4 s[2][4];
      #pragma unroll
      for (int mt = 0; mt < 4; ++mt) {
        bf16x8 kf = *(const bf16x8*)&Ks[kl + mt * 16 + l16][quad * 8];
        s[0][mt] = __builtin_amdgcn_mfma_f32_16x16x32_bf16(kf, qf[0], zf, 0, 0, 0);
        s[1][mt] = __builtin_amdgcn_mfma_f32_16x16x32_bf16(kf, qf[1], zf, 0, 0, 0);
      }
      #pragma unroll
      for (int mt = 0; mt < 4; ++mt) {
        f32x4 md = *(const f32x4*)(maddb + kb0 + kl + mt * 16 + quad * 4);
        #pragma unroll
        for (int qg = 0; qg < 2; ++qg) {
          bf16x4 pv;
          #pragma unroll
          for (int r = 0; r < 4; ++r)
            pv[r] = (__bf16)__builtin_amdgcn_exp2f(fmaf(s[qg][mt][r], C2, md[r]));
          *(bf16x4*)&Ps[wave][qg][l16][mt * 16 + quad * 4] = pv;
        }
      }
      #pragma unroll
      for (int ks = 0; ks < 2; ++ks) {
        bf16x8 vf[2];
        #pragma unroll
        for (int nt = 0; nt < 2; ++nt)
          vf[nt] = *(const bf16x8*)&Vs[nt * 16 + l16][kl + ks * 32 + quad * 8];
        #pragma unroll
        for (int qg = 0; qg < 2; ++qg) {
          bf16x8 pf = *(const bf16x8*)&Ps[wave][qg][l16][ks * 32 + quad * 8];
          #pragma unroll
          for (int nt = 0; nt < 2; ++nt)
            o[qg][nt] = __builtin_amdgcn_mfma_f32_16x16x32_bf16(pf, vf[nt], o[qg][nt], 0, 0, 0);
          ol[qg] = __builtin_amdgcn_mfma_f32_16x16x32_bf16(pf, ones, ol[qg], 0, 0, 0);
        }
      }
    }
  }

  float* Op = Opart + (size_t)half * MTOK * DM;
  #pragma unroll
  for (int qg = 0; qg < 2; ++qg) {
    #pragma unroll
    for (int nt = 0; nt < 2; ++nt)
      #pragma unroll
      for (int r = 0; r < 4; ++r) {
        int q   = qw + qg * 16 + quad * 4 + r;
        int col = h * DH + nt * 16 + l16;
        Op[((size_t)(b * SEQ + q)) * DM + col] = o[qg][nt][r];
      }
    if (l16 == 0) {
      #pragma unroll
      for (int r = 0; r < 4; ++r)
        lpart[((((size_t)half * NB + b) * NH) + h) * SEQ + qw + qg * 16 + quad * 4 + r] = ol[qg][r];
    }
  }
}

// ---------------- launcher ----------------
extern "C" void kernel_launch(void* const* d_in, const int* in_sizes, int n_in,
                              void* d_out, int out_size, void* d_ws, size_t ws_size,
                              hipStream_t stream) {
  const float* tokens = (const float*)d_in[0];
  const unsigned char* mask = (const unsigned char*)d_in[1];
  const float* ln1g = (const float*)d_in[2];
  const float* ln1b = (const float*)d_in[3];
  const float* wq = (const float*)d_in[4];
  const float* bq = (const float*)d_in[5];
  const float* wk = (const float*)d_in[6];
  const float* bk = (const float*)d_in[7];
  const float* wv = (const float*)d_in[8];
  const float* bv = (const float*)d_in[9];
  const float* wo = (const float*)d_in[10];
  const float* bo = (const float*)d_in[11];
  const float* ln2g = (const float*)d_in[12];
  const float* ln2b = (const float*)d_in[13];
  const float* w1 = (const float*)d_in[14];
  const float* b1 = (const float*)d_in[15];
  const float* w2 = (const float*)d_in[16];
  const float* b2 = (const float*)d_in[17];
  float* out = (float*)d_out;
  char* ws = (char*)d_ws;

  __bf16* wqkvT = (__bf16*)(ws + 0);            // [768][256]
  __bf16* woT   = (__bf16*)(ws + 393216);       // [256][256]
  __bf16* w1T   = (__bf16*)(ws + 524288);       // [1024][256]
  __bf16* w2T   = (__bf16*)(ws + 1048576);      // [256][1024]
  __bf16* xn1   = (__bf16*)(ws + 1572864);      // [8192][256] (dead after QKV)
  float*  lpart = (float*)(ws + 1572864);       // [2][4][8][2048] fp32 (reuses xn1 region)
  __bf16* qb    = (__bf16*)(ws + 5767168);      // [32][2048][32]
  __bf16* kb    = (__bf16*)(ws + 9961472);
  __bf16* vt    = (__bf16*)(ws + 18350080);     // [32][32][2048]
  float*  x1    = (float*)(ws + 26738688);      // [8192][256] fp32
  __bf16* xn2   = (__bf16*)(ws + 35127296);     // [8192][256]
  __bf16* hbuf  = (__bf16*)(ws + 39321600);     // [8192][1024] (FF1 out)
  float*  Opart = (float*)(ws + 39321600);      // [2][8192][256] fp32, lifetime-disjoint w/ hbuf
  float*  madd  = (float*)(ws + 56098816);      // [4][2048] fp32

  prep_kernel<<<2848, 256, 0, stream>>>(
      wq, wk, wv, wo, w1, w2, mask, tokens, ln1g, ln1b,
      wqkvT, woT, w1T, w2T, madd, xn1);

  // QKV: reg-B GEMM, N=768, MITERS=2 -> 24*128/... = 3072 waves = 768 blocks
  gemm_regb<0, 2><<<768, 256, 0, stream>>>(
      xn1, wqkvT, 768, nullptr, bq, bk, bv,
      nullptr, nullptr, nullptr, qb, kb, vt, nullptr, nullptr);

  attn_kernel<<<dim3(32, SEQ / 128, 2), 256, 0, stream>>>(qb, kb, vt, madd, Opart, lpart);

  // Wo + residual + fused split-K reduce: N=256, MITERS=1 -> 2048 waves = 512 blocks
  gemm_regb<1, 1><<<512, 256, 0, stream>>>(
      nullptr, woT, 256, bo, nullptr, nullptr, nullptr,
      tokens, x1, nullptr, nullptr, nullptr, nullptr, Opart, lpart);

  ln_kernel<<<MTOK / 4, 256, 0, stream>>>(x1, ln2g, ln2b, xn2);

  // FF1 + GELU: N=1024, MITERS=2 -> 4096 waves = 1024 blocks
  gemm_regb<2, 2><<<1024, 256, 0, stream>>>(
      xn2, w1T, 1024, b1, nullptr, nullptr, nullptr,
      nullptr, nullptr, hbuf, nullptr, nullptr, nullptr, nullptr, nullptr);

  // FF2 (K=1024) keeps the LDS-staged GEMM
  gemm_bt<64, 64, 1><<<dim3(128, 4), 256, 0, stream>>>(
      hbuf, w2T, MTOK, 256, DFF, b2, x1, out);
}

// Round 13
// 187.269 us; speedup vs baseline: 1.2181x; 1.2181x over previous
//
#include <hip/hip_runtime.h>
#include <cmath>

typedef __attribute__((ext_vector_type(8))) __bf16 bf16x8;
typedef __attribute__((ext_vector_type(4))) __bf16 bf16x4;
typedef __attribute__((ext_vector_type(4))) float  f32x4;

constexpr int NB   = 4;
constexpr int SEQ  = 2048;
constexpr int DM   = 256;
constexpr int NH   = 8;
constexpr int DH   = 32;
constexpr int DFF  = 1024;
constexpr int MTOK = NB * SEQ;  // 8192

// ---------------- LayerNorm: fp32 [rows][256] -> bf16 [rows][256] ----------------
__global__ __launch_bounds__(256) void ln_kernel(const float* __restrict__ x,
                                                 const float* __restrict__ g,
                                                 const float* __restrict__ b,
                                                 __bf16* __restrict__ out) {
  int wave = threadIdx.x >> 6, lane = threadIdx.x & 63;
  int row = blockIdx.x * 4 + wave;
  const float* xr = x + (size_t)row * DM;
  f32x4 v = *(const f32x4*)(xr + lane * 4);
  float s  = v[0] + v[1] + v[2] + v[3];
  float sq = v[0]*v[0] + v[1]*v[1] + v[2]*v[2] + v[3]*v[3];
  #pragma unroll
  for (int off = 1; off < 64; off <<= 1) {
    s  += __shfl_xor(s, off);
    sq += __shfl_xor(sq, off);
  }
  float mu  = s * (1.0f / DM);
  float var = sq * (1.0f / DM) - mu * mu;
  float rs  = rsqrtf(var + 1e-5f);
  f32x4 gv = *(const f32x4*)(g + lane * 4);
  f32x4 bv = *(const f32x4*)(b + lane * 4);
  bf16x4 o;
  #pragma unroll
  for (int i = 0; i < 4; ++i) o[i] = (__bf16)((v[i] - mu) * rs * gv[i] + bv[i]);
  *(bf16x4*)(out + (size_t)row * DM + lane * 4) = o;
}

// ---------------- Fused prep, TIGHT 1D grid (2848 blocks) ----------------
__global__ __launch_bounds__(256) void prep_kernel(
    const float* __restrict__ wq, const float* __restrict__ wk, const float* __restrict__ wv,
    const float* __restrict__ wo, const float* __restrict__ w1, const float* __restrict__ w2,
    const unsigned char* __restrict__ mask, const float* __restrict__ tokens,
    const float* __restrict__ ln1g, const float* __restrict__ ln1b,
    __bf16* __restrict__ wqkvT, __bf16* __restrict__ woT,
    __bf16* __restrict__ w1T, __bf16* __restrict__ w2T,
    float* __restrict__ madd_g, __bf16* __restrict__ xn1) {
  __shared__ float tile[32][33];
  int bid = blockIdx.x;
  int tid = threadIdx.x;
  if (bid >= 800) {
    int row = (bid - 800) * 4 + (tid >> 6);
    int lane = tid & 63;
    const float* xr = tokens + (size_t)row * DM;
    f32x4 v = *(const f32x4*)(xr + lane * 4);
    float s  = v[0] + v[1] + v[2] + v[3];
    float sq = v[0]*v[0] + v[1]*v[1] + v[2]*v[2] + v[3]*v[3];
    #pragma unroll
    for (int off = 1; off < 64; off <<= 1) {
      s  += __shfl_xor(s, off);
      sq += __shfl_xor(sq, off);
    }
    float mu  = s * (1.0f / DM);
    float var = sq * (1.0f / DM) - mu * mu;
    float rs  = rsqrtf(var + 1e-5f);
    f32x4 gv = *(const f32x4*)(ln1g + lane * 4);
    f32x4 bv = *(const f32x4*)(ln1b + lane * 4);
    bf16x4 o;
    #pragma unroll
    for (int i = 0; i < 4; ++i) o[i] = (__bf16)((v[i] - mu) * rs * gv[i] + bv[i]);
    *(bf16x4*)(xn1 + (size_t)row * DM + lane * 4) = o;
    return;
  }
  if (bid >= 768) {
    int idx = (bid - 768) * 256 + tid;
    madd_g[idx] = mask[idx] ? -__builtin_inff() : 0.0f;
    return;
  }
  const float* W; __bf16* Wt; int K, N, n0, k0;
  if (bid < 256) {
    int z = bid >> 6, local = bid & 63;
    K = 256; N = 256;
    n0 = (local & 7) * 32; k0 = (local >> 3) * 32;
    if      (z == 0) { W = wq; Wt = wqkvT;          }
    else if (z == 1) { W = wk; Wt = wqkvT + 65536;  }
    else if (z == 2) { W = wv; Wt = wqkvT + 131072; }
    else             { W = wo; Wt = woT;            }
  } else if (bid < 512) {
    int local = bid - 256;
    W = w1; Wt = w1T; K = 256; N = 1024;
    n0 = (local & 31) * 32; k0 = (local >> 5) * 32;
  } else {
    int local = bid - 512;
    W = w2; Wt = w2T; K = 1024; N = 256;
    n0 = (local & 7) * 32; k0 = (local >> 3) * 32;
  }
  {
    int kl = tid >> 3, n4 = (tid & 7) * 4;
    f32x4 v = *(const f32x4*)(W + (size_t)(k0 + kl) * N + n0 + n4);
    tile[kl][n4 + 0] = v[0]; tile[kl][n4 + 1] = v[1];
    tile[kl][n4 + 2] = v[2]; tile[kl][n4 + 3] = v[3];
  }
  __syncthreads();
  {
    int nl = tid >> 3, k4 = (tid & 7) * 4;
    bf16x4 o;
    #pragma unroll
    for (int i = 0; i < 4; ++i) o[i] = (__bf16)tile[k4 + i][nl];
    *(bf16x4*)(Wt + (size_t)(n0 + nl) * K + k0 + k4) = o;
  }
}

// ---------------- GEMM: C[M][N] = A[M][K](bf16) * Bt[N][K]^T + epilogue ----------------
// AF=1: A built on the fly from split-K attention partials.
template<int BM, int BN, int EP, int AF = 0>
__global__ __launch_bounds__(256) void gemm_bt(
    const __bf16* __restrict__ A, const __bf16* __restrict__ Bt,
    int M, int N, int K,
    const float* __restrict__ bias,
    const float* __restrict__ bq, const float* __restrict__ bk, const float* __restrict__ bv,
    const float* __restrict__ resid, float* __restrict__ outf,
    __bf16* __restrict__ outb,
    __bf16* __restrict__ outq, __bf16* __restrict__ outk, __bf16* __restrict__ outv,
    const float* __restrict__ Af = nullptr, const float* __restrict__ lpart = nullptr) {
  constexpr int MT = BM / 32, NT = BN / 32;
  constexpr int AP = BM / 32, BP = BN / 32;
  __shared__ __bf16 As[BM * 64];
  __shared__ __bf16 Bs[BN * 64];
  int tid = threadIdx.x;
  int wave = tid >> 6, lane = tid & 63;
  int wm = wave >> 1, wn = wave & 1;
  int quad = lane >> 4, l16 = lane & 15;
  int m0 = blockIdx.x * BM, n0 = blockIdx.y * BN;
  int lrow = lane >> 3;
  int lcg  = ((lane & 7) ^ lrow) * 8;

  auto loadA = [&](int rbase, int kcol) -> bf16x8 {
    int gr = m0 + rbase + lrow;
    if constexpr (AF == 0) {
      return *(const bf16x8*)(A + (size_t)gr * K + kcol);
    } else {
      const float* p0 = Af + (size_t)gr * K + kcol;
      const float* p1 = p0 + (size_t)MTOK * DM;
      f32x4 a0 = *(const f32x4*)p0, a0b = *(const f32x4*)(p0 + 4);
      f32x4 a1 = *(const f32x4*)p1, a1b = *(const f32x4*)(p1 + 4);
      int bb = gr >> 11, tok = gr & 2047, hh = kcol >> 5;
      float l = lpart[((size_t)bb * NH + hh) * SEQ + tok] +
                lpart[(((size_t)NB + bb) * NH + hh) * SEQ + tok];
      float inv = 1.0f / l;
      bf16x8 o;
      #pragma unroll
      for (int i = 0; i < 4; ++i) {
        o[i]     = (__bf16)((a0[i]  + a1[i])  * inv);
        o[i + 4] = (__bf16)((a0b[i] + a1b[i]) * inv);
      }
      return o;
    }
  };

  f32x4 acc[MT][NT];
  #pragma unroll
  for (int mt = 0; mt < MT; ++mt)
    #pragma unroll
    for (int nt = 0; nt < NT; ++nt)
      #pragma unroll
      for (int r = 0; r < 4; ++r) acc[mt][nt][r] = 0.0f;

  bf16x8 ap[AP], bp[BP];
  #pragma unroll
  for (int i = 0; i < AP; ++i) ap[i] = loadA(wave * (BM / 4) + i * 8, lcg);
  #pragma unroll
  for (int i = 0; i < BP; ++i) {
    int rbase = wave * (BN / 4) + i * 8;
    bp[i] = *(const bf16x8*)(Bt + (size_t)(n0 + rbase + lrow) * K + lcg);
  }
  #pragma unroll
  for (int i = 0; i < AP; ++i) {
    int rbase = wave * (BM / 4) + i * 8;
    *(bf16x8*)&As[rbase * 64 + lane * 8] = ap[i];
  }
  #pragma unroll
  for (int i = 0; i < BP; ++i) {
    int rbase = wave * (BN / 4) + i * 8;
    *(bf16x8*)&Bs[rbase * 64 + lane * 8] = bp[i];
  }
  __syncthreads();

  for (int kt = 0; kt < K; kt += 64) {
    bool more = (kt + 64) < K;
    if (more) {
      #pragma unroll
      for (int i = 0; i < AP; ++i) ap[i] = loadA(wave * (BM / 4) + i * 8, kt + 64 + lcg);
      #pragma unroll
      for (int i = 0; i < BP; ++i) {
        int rbase = wave * (BN / 4) + i * 8;
        bp[i] = *(const bf16x8*)(Bt + (size_t)(n0 + rbase + lrow) * K + kt + 64 + lcg);
      }
    }
    #pragma unroll
    for (int ks = 0; ks < 2; ++ks) {
      bf16x8 af[MT], bfr[NT];
      #pragma unroll
      for (int mt = 0; mt < MT; ++mt) {
        int row = wm * (BM / 2) + mt * 16 + l16;
        af[mt] = *(const bf16x8*)&As[row * 64 + (((ks * 4 + quad) ^ (l16 & 7)) * 8)];
      }
      #pragma unroll
      for (int nt = 0; nt < NT; ++nt) {
        int row = wn * (BN / 2) + nt * 16 + l16;
        bfr[nt] = *(const bf16x8*)&Bs[row * 64 + (((ks * 4 + quad) ^ (l16 & 7)) * 8)];
      }
      #pragma unroll
      for (int mt = 0; mt < MT; ++mt)
        #pragma unroll
        for (int nt = 0; nt < NT; ++nt)
          acc[mt][nt] = __builtin_amdgcn_mfma_f32_16x16x32_bf16(af[mt], bfr[nt], acc[mt][nt], 0, 0, 0);
    }
    if (more) {
      __syncthreads();
      #pragma unroll
      for (int i = 0; i < AP; ++i) {
        int rbase = wave * (BM / 4) + i * 8;
        *(bf16x8*)&As[rbase * 64 + lane * 8] = ap[i];
      }
      #pragma unroll
      for (int i = 0; i < BP; ++i) {
        int rbase = wave * (BN / 4) + i * 8;
        *(bf16x8*)&Bs[rbase * 64 + lane * 8] = bp[i];
      }
      __syncthreads();
    }
  }

  #pragma unroll
  for (int mt = 0; mt < MT; ++mt)
  #pragma unroll
  for (int nt = 0; nt < NT; ++nt)
  #pragma unroll
  for (int r = 0; r < 4; ++r) {
    int gm = m0 + wm * (BM / 2) + mt * 16 + quad * 4 + r;
    int gn = n0 + wn * (BN / 2) + nt * 16 + l16;
    float v = acc[mt][nt][r];
    if constexpr (EP == 0) {
      int which = gn >> 8, nn = gn & 255;
      const float* bp2 = which == 0 ? bq : (which == 1 ? bk : bv);
      v += bp2[nn];
      int h = nn >> 5, hd = nn & 31;
      int bb = gm >> 11, tok = gm & 2047;
      if (which == 2) {
        outv[(((size_t)(bb * NH + h)) * DH + hd) * SEQ + tok] = (__bf16)v;
      } else {
        __bf16* dst = which == 0 ? outq : outk;
        dst[(((size_t)(bb * NH + h)) * SEQ + tok) * DH + hd] = (__bf16)v;
      }
    } else if constexpr (EP == 1) {
      v += bias[gn] + resid[(size_t)gm * N + gn];
      outf[(size_t)gm * N + gn] = v;
    } else {
      v += bias[gn];
      float v2 = v * v;
      float t = __builtin_amdgcn_exp2f(v * (2.3022082f + 0.10294324f * v2));
      outb[(size_t)gm * N + gn] = (__bf16)(v * t * __builtin_amdgcn_rcpf(t + 1.0f));
    }
  }
}

// ---------------- Flash attention: 32 q/wave, shared 128-key stages, split-K=2 ----------------
// R10 structure; grid swizzled so the 16 consecutively-dispatched blocks share one
// bh's 256 KB K/V working set (per-XCD L2 locality): x=q-chunk (fast), y=bh.
__global__ __launch_bounds__(256) void attn_kernel(
    const __bf16* __restrict__ Q, const __bf16* __restrict__ K,
    const __bf16* __restrict__ Vt, const float* __restrict__ madd_g,
    float* __restrict__ Opart, float* __restrict__ lpart) {
  constexpr float C2 = 0.2550350030061664f;  // (1/sqrt(32)) * log2(e)
  __shared__ __bf16 Ks[128][36];      // [key][dh], 72B stride
  __shared__ __bf16 Vs[32][132];      // [dh][key], 264B stride
  __shared__ __bf16 Ps[4][2][16][68]; // [wave][qg][query][key]
  int bh = blockIdx.y;
  int q0 = blockIdx.x * 128;
  int half = blockIdx.z;
  int b  = bh >> 3, h = bh & 7;
  int tid = threadIdx.x;
  int wave = tid >> 6, lane = tid & 63;
  int quad = lane >> 4, l16 = lane & 15;
  const __bf16* Qb = Q  + (size_t)bh * SEQ * DH;
  const __bf16* Kb = K  + (size_t)bh * SEQ * DH;
  const __bf16* Vb = Vt + (size_t)bh * DH * SEQ;
  const float* maddb = madd_g + b * SEQ;
  int qw = q0 + wave * 32;
  int kbase = half * (SEQ / 2);

  bf16x8 qf[2];
  #pragma unroll
  for (int qg = 0; qg < 2; ++qg)
    qf[qg] = *(const bf16x8*)(Qb + (size_t)(qw + qg * 16 + l16) * DH + quad * 8);

  bf16x8 ones;
  #pragma unroll
  for (int i = 0; i < 8; ++i) ones[i] = (__bf16)1.0f;

  f32x4 o[2][2], ol[2];
  #pragma unroll
  for (int qg = 0; qg < 2; ++qg) {
    #pragma unroll
    for (int nt = 0; nt < 2; ++nt)
      #pragma unroll
      for (int r = 0; r < 4; ++r) o[qg][nt][r] = 0.0f;
    #pragma unroll
    for (int r = 0; r < 4; ++r) ol[qg][r] = 0.0f;
  }

  f32x4 zf; zf[0] = zf[1] = zf[2] = zf[3] = 0.0f;

  for (int st = 0; st < 8; ++st) {          // 8 stages x 128 keys = this half
    int kb0 = kbase + st * 128;
    __syncthreads();
    #pragma unroll
    for (int p = 0; p < 2; ++p) {           // stage K: 128 rows x 64B
      int c = p * 256 + tid, row = c >> 2, cg = (c & 3) * 8;
      *(bf16x8*)&Ks[row][cg] = *(const bf16x8*)(Kb + (size_t)(kb0 + row) * DH + cg);
    }
    #pragma unroll
    for (int p = 0; p < 2; ++p) {           // stage V: 32 rows x 256B
      int c = p * 256 + tid, row = c >> 4, cg = (c & 15) * 8;
      *(bf16x8*)&Vs[row][cg] = *(const bf16x8*)(Vb + (size_t)row * SEQ + kb0 + cg);
    }
    __syncthreads();

    #pragma unroll
    for (int sub = 0; sub < 2; ++sub) {     // 2 x 64-key subtiles
      int kl = sub * 64;
      f32x4 s[2][4];
      #pragma unroll
      for (int mt = 0; mt < 4; ++mt) {
        bf16x8 kf = *(const bf16x8*)&Ks[kl + mt * 16 + l16][quad * 8];
        s[0][mt] = __builtin_amdgcn_mfma_f32_16x16x32_bf16(kf, qf[0], zf, 0, 0, 0);
        s[1][mt] = __builtin_amdgcn_mfma_f32_16x16x32_bf16(kf, qf[1], zf, 0, 0, 0);
      }
      #pragma unroll
      for (int mt = 0; mt < 4; ++mt) {
        f32x4 md = *(const f32x4*)(maddb + kb0 + kl + mt * 16 + quad * 4);
        #pragma unroll
        for (int qg = 0; qg < 2; ++qg) {
          bf16x4 pv;
          #pragma unroll
          for (int r = 0; r < 4; ++r)
            pv[r] = (__bf16)__builtin_amdgcn_exp2f(fmaf(s[qg][mt][r], C2, md[r]));
          *(bf16x4*)&Ps[wave][qg][l16][mt * 16 + quad * 4] = pv;
        }
      }
      #pragma unroll
      for (int ks = 0; ks < 2; ++ks) {
        bf16x8 vf[2];
        #pragma unroll
        for (int nt = 0; nt < 2; ++nt)
          vf[nt] = *(const bf16x8*)&Vs[nt * 16 + l16][kl + ks * 32 + quad * 8];
        #pragma unroll
        for (int qg = 0; qg < 2; ++qg) {
          bf16x8 pf = *(const bf16x8*)&Ps[wave][qg][l16][ks * 32 + quad * 8];
          #pragma unroll
          for (int nt = 0; nt < 2; ++nt)
            o[qg][nt] = __builtin_amdgcn_mfma_f32_16x16x32_bf16(pf, vf[nt], o[qg][nt], 0, 0, 0);
          ol[qg] = __builtin_amdgcn_mfma_f32_16x16x32_bf16(pf, ones, ol[qg], 0, 0, 0);
        }
      }
    }
  }

  float* Op = Opart + (size_t)half * MTOK * DM;
  #pragma unroll
  for (int qg = 0; qg < 2; ++qg) {
    #pragma unroll
    for (int nt = 0; nt < 2; ++nt)
      #pragma unroll
      for (int r = 0; r < 4; ++r) {
        int q   = qw + qg * 16 + quad * 4 + r;
        int col = h * DH + nt * 16 + l16;
        Op[((size_t)(b * SEQ + q)) * DM + col] = o[qg][nt][r];
      }
    if (l16 == 0) {
      #pragma unroll
      for (int r = 0; r < 4; ++r)
        lpart[((((size_t)half * NB + b) * NH) + h) * SEQ + qw + qg * 16 + quad * 4 + r] = ol[qg][r];
    }
  }
}

// ---------------- launcher ----------------
extern "C" void kernel_launch(void* const* d_in, const int* in_sizes, int n_in,
                              void* d_out, int out_size, void* d_ws, size_t ws_size,
                              hipStream_t stream) {
  const float* tokens = (const float*)d_in[0];
  const unsigned char* mask = (const unsigned char*)d_in[1];
  const float* ln1g = (const float*)d_in[2];
  const float* ln1b = (const float*)d_in[3];
  const float* wq = (const float*)d_in[4];
  const float* bq = (const float*)d_in[5];
  const float* wk = (const float*)d_in[6];
  const float* bk = (const float*)d_in[7];
  const float* wv = (const float*)d_in[8];
  const float* bv = (const float*)d_in[9];
  const float* wo = (const float*)d_in[10];
  const float* bo = (const float*)d_in[11];
  const float* ln2g = (const float*)d_in[12];
  const float* ln2b = (const float*)d_in[13];
  const float* w1 = (const float*)d_in[14];
  const float* b1 = (const float*)d_in[15];
  const float* w2 = (const float*)d_in[16];
  const float* b2 = (const float*)d_in[17];
  float* out = (float*)d_out;
  char* ws = (char*)d_ws;

  __bf16* wqkvT = (__bf16*)(ws + 0);            // [768][256]
  __bf16* woT   = (__bf16*)(ws + 393216);       // [256][256]
  __bf16* w1T   = (__bf16*)(ws + 524288);       // [1024][256]
  __bf16* w2T   = (__bf16*)(ws + 1048576);      // [256][1024]
  __bf16* xn1   = (__bf16*)(ws + 1572864);      // [8192][256] (dead after QKV)
  float*  lpart = (float*)(ws + 1572864);       // [2][4][8][2048] fp32 (reuses xn1 region)
  __bf16* qb    = (__bf16*)(ws + 5767168);      // [32][2048][32]
  __bf16* kb    = (__bf16*)(ws + 9961472);
  __bf16* vt    = (__bf16*)(ws + 18350080);     // [32][32][2048]
  float*  x1    = (float*)(ws + 26738688);      // [8192][256] fp32
  __bf16* xn2   = (__bf16*)(ws + 35127296);     // [8192][256]
  __bf16* hbuf  = (__bf16*)(ws + 39321600);     // [8192][1024] (FF1 out)
  float*  Opart = (float*)(ws + 39321600);      // [2][8192][256] fp32, lifetime-disjoint w/ hbuf
  float*  madd  = (float*)(ws + 56098816);      // [4][2048] fp32

  prep_kernel<<<2848, 256, 0, stream>>>(
      wq, wk, wv, wo, w1, w2, mask, tokens, ln1g, ln1b,
      wqkvT, woT, w1T, w2T, madd, xn1);

  gemm_bt<128, 64, 0><<<dim3(64, 12), 256, 0, stream>>>(
      xn1, wqkvT, MTOK, 768, 256, nullptr, bq, bk, bv,
      nullptr, nullptr, nullptr, qb, kb, vt);

  // L2-locality swizzle: q-chunk fastest, bh second
  attn_kernel<<<dim3(SEQ / 128, 32, 2), 256, 0, stream>>>(qb, kb, vt, madd, Opart, lpart);

  gemm_bt<64, 64, 1, 1><<<dim3(128, 4), 256, 0, stream>>>(
      nullptr, woT, MTOK, 256, 256, bo, nullptr, nullptr, nullptr,
      tokens, x1, nullptr, nullptr, nullptr, nullptr, Opart, lpart);

  ln_kernel<<<MTOK / 4, 256, 0, stream>>>(x1, ln2g, ln2b, xn2);

  gemm_bt<128, 128, 2><<<dim3(64, 8), 256, 0, stream>>>(
      xn2, w1T, MTOK, DFF, 256, b1, nullptr, nullptr, nullptr,
      nullptr, nullptr, hbuf, nullptr, nullptr, nullptr);

  gemm_bt<64, 64, 1><<<dim3(128, 4), 256, 0, stream>>>(
      hbuf, w2T, MTOK, 256, DFF, b2, nullptr, nullptr, nullptr,
      x1, out, nullptr, nullptr, nullptr, nullptr);
}